// Round 1
// 550.915 us; speedup vs baseline: 1.0897x; 1.0897x over previous
//
#include <hip/hip_runtime.h>

#define VOCAB 32000
#define EMBED 128
#define CTX 8
#define BATCH 4096

typedef short bf16x8 __attribute__((ext_vector_type(8)));
typedef float f32x4 __attribute__((ext_vector_type(4)));

__device__ __forceinline__ unsigned short f2bf_rne(float f) {
    union { float f; unsigned int u; } v; v.f = f;
    unsigned int u = v.u;
    unsigned int r = (u + 0x7FFFu + ((u >> 16) & 1u)) >> 16;
    return (unsigned short)r;
}

// Kernel 1: CBOW gather-sum (padding_idx=0) + fp32->bf16 convert.
__global__ void gather_sum_kernel(const int* __restrict__ x,
                                  const float* __restrict__ emb,
                                  unsigned short* __restrict__ A) {
    const int i = blockIdx.x;    // sample
    const int j = threadIdx.x;   // embed dim 0..127
    const int* xr = x + i * CTX;
    float s = 0.0f;
#pragma unroll
    for (int c = 0; c < CTX; ++c) {
        const int idx = xr[c];          // uniform across block
        if (idx != 0) s += emb[(size_t)idx * EMBED + j];
    }
    A[i * EMBED + j] = f2bf_rne(s);
}

// Kernel 2: W fp32 -> bf16.
__global__ void convert_w_kernel(const float* __restrict__ W,
                                 unsigned short* __restrict__ Wb) {
    const int t = blockIdx.x * 256 + threadIdx.x;
    const float4 v = ((const float4*)W)[t];
    ushort4 o;
    o.x = f2bf_rne(v.x);
    o.y = f2bf_rne(v.y);
    o.z = f2bf_rne(v.z);
    o.w = f2bf_rne(v.w);
    ((ushort4*)Wb)[t] = o;
}

// Kernel 3: C[4096,32000] = A[4096,128] @ Wb[32000,128]^T + bias.
// R2: LDS-transpose epilogue. The old epilogue's store instructions wrote
// 16 rows x 64B half-lines (lane&15 -> batch row, 128KB stride) with nt
// flag -> partial-line writebacks / write amplification; GEMM ran at
// ~1-2 TB/s vs the fill kernel's 6.35 TB/s on the same buffer. Now each
// m-tile's 64x256 output is staged to LDS (row pad +4 floats -> bank
// rotation, write scatter is bank-uniform), then each wave-instruction
// stores one full 1KB-aligned 1KB row chunk = 8 full 128B lines.
#define LDS_STRIDE 260   // 256 cols + 4-float pad (rotates banks by 4/row)

__global__ __launch_bounds__(256, 2) void cbow_gemm_kernel(
    const unsigned short* __restrict__ A,    // [BATCH][128] bf16 (summed)
    const unsigned short* __restrict__ Wb,   // [VOCAB][128] bf16
    const float* __restrict__ bias,          // [VOCAB]
    float* __restrict__ C)                   // [BATCH][VOCAB]
{
    __shared__ float tile[64 * LDS_STRIDE];  // 65 KB; 2 blocks/CU = 130 KB

    const int tid  = threadIdx.x;
    const int wave = tid >> 6;
    const int lane = tid & 63;
    const int lr   = lane & 15;   // free-dim index inside 16x16 tile
    const int quad = lane >> 4;   // k-chunk / output-col selector
    const int nwave = blockIdx.x * 256 + wave * 64;  // vocab start, this wave
    const int cbase = blockIdx.x * 256;              // vocab start, block

    // W fragments: loaded ONCE, live for the whole block. 64 VGPRs.
    bf16x8 wf[4][4];
#pragma unroll
    for (int nt = 0; nt < 4; ++nt) {
        const unsigned short* wrow =
            Wb + (size_t)(nwave + nt * 16 + lr) * EMBED;
#pragma unroll
        for (int s = 0; s < 4; ++s)
            wf[nt][s] = *(const bf16x8*)(wrow + s * 32 + quad * 8);
    }

    // Bias, loaded once. acc col n = nwave + nt*16 + quad*4 + reg.
    f32x4 bv[4];
#pragma unroll
    for (int nt = 0; nt < 4; ++nt)
        bv[nt] = *(const f32x4*)(bias + nwave + nt * 16 + quad * 4);

    // Loop over this block's 8 m-tiles (512 batch rows per block).
    for (int mb = 0; mb < 8; ++mb) {
        const int mbase = (blockIdx.y * 8 + mb) * 64;

        // B-operand frags: summed[m][k]; n_mfma = lr -> batch row.
        bf16x8 bfrag[4][4];
#pragma unroll
        for (int mt = 0; mt < 4; ++mt) {
            const unsigned short* row =
                A + (size_t)(mbase + mt * 16 + lr) * EMBED;
#pragma unroll
            for (int s = 0; s < 4; ++s)
                bfrag[mt][s] = *(const bf16x8*)(row + s * 32 + quad * 8);
        }

        f32x4 acc[4][4];
#pragma unroll
        for (int nt = 0; nt < 4; ++nt)
#pragma unroll
            for (int mt = 0; mt < 4; ++mt)
                acc[nt][mt] = (f32x4){0.f, 0.f, 0.f, 0.f};

#pragma unroll
        for (int nt = 0; nt < 4; ++nt)
#pragma unroll
            for (int s = 0; s < 4; ++s)
#pragma unroll
                for (int mt = 0; mt < 4; ++mt)
                    acc[nt][mt] = __builtin_amdgcn_mfma_f32_16x16x32_bf16(
                        wf[nt][s], bfrag[mt][s], acc[nt][mt], 0, 0, 0);

        // Stage to LDS with bias added.
        // acc[nt][mt][reg] = C[mbase + mt*16 + lr][nwave + nt*16 + quad*4 + reg]
        // LDS row = within-tile batch row (0..63), col = within-block vocab
        // col (0..255). Bank of f32x4 write = 4*((lr + quad + 4*nt) % 8):
        // uniform 8 lanes per 4-bank group = minimum for b128 x 64 lanes.
#pragma unroll
        for (int nt = 0; nt < 4; ++nt)
#pragma unroll
            for (int mt = 0; mt < 4; ++mt) {
                const f32x4 v = acc[nt][mt] + bv[nt];
                *(f32x4*)&tile[(mt * 16 + lr) * LDS_STRIDE +
                               wave * 64 + nt * 16 + quad * 4] = v;
            }
        __syncthreads();

        // Coalesced store: one wave-instruction = one full row chunk.
        // 64 lanes x 16B = 1KB contiguous, 1KB-aligned (cbase*4 = 1KB mult,
        // row start 128KB-aligned) -> 8 full 128B lines per instruction.
#pragma unroll
        for (int i = 0; i < 16; ++i) {
            const int r = wave * 16 + i;
            const f32x4 v = *(const f32x4*)&tile[r * LDS_STRIDE + lane * 4];
            __builtin_nontemporal_store(
                v, (f32x4*)(C + (size_t)(mbase + r) * VOCAB + cbase + lane * 4));
        }
        __syncthreads();  // tile reused next m-tile
    }
}

extern "C" void kernel_launch(void* const* d_in, const int* in_sizes, int n_in,
                              void* d_out, int out_size, void* d_ws, size_t ws_size,
                              hipStream_t stream) {
    const int*   x    = (const int*)d_in[0];     // [4096,8]
    const float* emb  = (const float*)d_in[1];   // [32000,128]
    const float* W    = (const float*)d_in[2];   // [32000,128]
    const float* bias = (const float*)d_in[3];   // [32000]
    float* out = (float*)d_out;                  // [4096,32000]

    unsigned short* A  = (unsigned short*)d_ws;            // 1 MB: summed bf16
    unsigned short* Wb = A + (size_t)BATCH * EMBED;        // 8.2 MB: W bf16

    gather_sum_kernel<<<BATCH, EMBED, 0, stream>>>(x, emb, A);
    convert_w_kernel<<<(VOCAB * EMBED / 4) / 256, 256, 0, stream>>>(W, Wb);

    dim3 grid(VOCAB / 256, BATCH / (8 * 64));   // 125 x 8 = 1000 blocks
    cbow_gemm_kernel<<<grid, 256, 0, stream>>>(A, Wb, bias, out);
}

// Round 2
// 546.520 us; speedup vs baseline: 1.0985x; 1.0080x over previous
//
#include <hip/hip_runtime.h>

#define VOCAB 32000
#define EMBED 128
#define CTX 8
#define BATCH 4096

typedef short bf16x8 __attribute__((ext_vector_type(8)));
typedef float f32x4 __attribute__((ext_vector_type(4)));

__device__ __forceinline__ unsigned short f2bf_rne(float f) {
    union { float f; unsigned int u; } v; v.f = f;
    unsigned int u = v.u;
    unsigned int r = (u + 0x7FFFu + ((u >> 16) & 1u)) >> 16;
    return (unsigned short)r;
}

// Kernel 1: CBOW gather-sum (padding_idx=0) + fp32->bf16 convert.
__global__ void gather_sum_kernel(const int* __restrict__ x,
                                  const float* __restrict__ emb,
                                  unsigned short* __restrict__ A) {
    const int i = blockIdx.x;    // sample
    const int j = threadIdx.x;   // embed dim 0..127
    const int* xr = x + i * CTX;
    float s = 0.0f;
#pragma unroll
    for (int c = 0; c < CTX; ++c) {
        const int idx = xr[c];          // uniform across block
        if (idx != 0) s += emb[(size_t)idx * EMBED + j];
    }
    A[i * EMBED + j] = f2bf_rne(s);
}

// Kernel 2: W fp32 -> bf16.
__global__ void convert_w_kernel(const float* __restrict__ W,
                                 unsigned short* __restrict__ Wb) {
    const int t = blockIdx.x * 256 + threadIdx.x;
    const float4 v = ((const float4*)W)[t];
    ushort4 o;
    o.x = f2bf_rne(v.x);
    o.y = f2bf_rne(v.y);
    o.z = f2bf_rne(v.z);
    o.w = f2bf_rne(v.w);
    ((ushort4*)Wb)[t] = o;
}

// Kernel 3: C[4096,32000] = A[4096,128] @ Wb[32000,128]^T + bias.
// R3: BARRIER-FREE epilogue. R2's __syncthreads pair per m-tile forced
// s_waitcnt vmcnt(0) (compiler drains ALL stores before s_barrier) -> the
// 64KB of nt-stores per m-tile had to fully reach HBM before the next
// tile's MFMAs could start; store pipe and compute never overlapped.
// Now each wave stages its OWN 64x64 f32 sub-tile into a wave-private LDS
// region and reads back its own region: no cross-wave dependency, zero
// barriers, stores drain asynchronously under the next m-tile's compute.
// Store instructions: 4 rows x 256B contiguous 256B-aligned chunks
// = 2 full 128B lines per chunk (full-line writeback preserved).
#define LDSW 68   // 64 cols + 4-float pad: both LDS phases hit the
                  // 8-lanes-per-4-bank-window minimum (conflict-free)

__global__ __launch_bounds__(256, 2) void cbow_gemm_kernel(
    const unsigned short* __restrict__ A,    // [BATCH][128] bf16 (summed)
    const unsigned short* __restrict__ Wb,   // [VOCAB][128] bf16
    const float* __restrict__ bias,          // [VOCAB]
    float* __restrict__ C)                   // [BATCH][VOCAB]
{
    __shared__ float tile[4 * 64 * LDSW];    // 4 waves x 17,408 B = 69,632 B

    const int tid  = threadIdx.x;
    const int wave = tid >> 6;
    const int lane = tid & 63;
    const int lr   = lane & 15;   // free-dim index inside 16x16 tile
    const int quad = lane >> 4;   // k-chunk / output-col selector
    const int nwave = blockIdx.x * 256 + wave * 64;  // vocab start, this wave
    float* wt = tile + wave * (64 * LDSW);           // wave-private region

    // W fragments: loaded ONCE, live for the whole block. 64 VGPRs.
    bf16x8 wf[4][4];
#pragma unroll
    for (int nt = 0; nt < 4; ++nt) {
        const unsigned short* wrow =
            Wb + (size_t)(nwave + nt * 16 + lr) * EMBED;
#pragma unroll
        for (int s = 0; s < 4; ++s)
            wf[nt][s] = *(const bf16x8*)(wrow + s * 32 + quad * 8);
    }

    // Bias, loaded once. acc col n = nwave + nt*16 + quad*4 + reg.
    f32x4 bv[4];
#pragma unroll
    for (int nt = 0; nt < 4; ++nt)
        bv[nt] = *(const f32x4*)(bias + nwave + nt * 16 + quad * 4);

    // Loop over this block's 8 m-tiles (512 batch rows per block).
    for (int mb = 0; mb < 8; ++mb) {
        const int mbase = (blockIdx.y * 8 + mb) * 64;

        // B-operand frags: summed[m][k]; n_mfma = lr -> batch row.
        bf16x8 bfrag[4][4];
#pragma unroll
        for (int mt = 0; mt < 4; ++mt) {
            const unsigned short* row =
                A + (size_t)(mbase + mt * 16 + lr) * EMBED;
#pragma unroll
            for (int s = 0; s < 4; ++s)
                bfrag[mt][s] = *(const bf16x8*)(row + s * 32 + quad * 8);
        }

        f32x4 acc[4][4];
#pragma unroll
        for (int nt = 0; nt < 4; ++nt)
#pragma unroll
            for (int mt = 0; mt < 4; ++mt)
                acc[nt][mt] = (f32x4){0.f, 0.f, 0.f, 0.f};

#pragma unroll
        for (int nt = 0; nt < 4; ++nt)
#pragma unroll
            for (int s = 0; s < 4; ++s)
#pragma unroll
                for (int mt = 0; mt < 4; ++mt)
                    acc[nt][mt] = __builtin_amdgcn_mfma_f32_16x16x32_bf16(
                        wf[nt][s], bfrag[mt][s], acc[nt][mt], 0, 0, 0);

        // Stage to wave-private LDS with bias added.
        // acc[nt][mt][reg] = C[mbase+mt*16+lr][nwave+nt*16+quad*4+reg]
        // local row rm = mt*16+lr (0..63), local col cn = nt*16+quad*4.
#pragma unroll
        for (int nt = 0; nt < 4; ++nt)
#pragma unroll
            for (int mt = 0; mt < 4; ++mt) {
                const f32x4 v = acc[nt][mt] + bv[nt];
                *(f32x4*)&wt[(mt * 16 + lr) * LDSW + nt * 16 + quad * 4] = v;
            }

        // Same-wave DS ops execute in order; cheap insurance drain of the
        // ds_writes (does NOT touch vmcnt -> global stores keep flowing).
        asm volatile("s_waitcnt lgkmcnt(0)" ::: "memory");

        // Read back own region + nontemporal store. Per instruction:
        // 4 rows x 256B contiguous (rows r=i*4+quad, cols lr*4..lr*4+3),
        // each chunk 256B-aligned = 2 full 128B lines. NO barrier: next
        // m-tile's ds_writes are same-wave (in-order) and store-source
        // VGPRs are compiler-tracked via vmcnt.
#pragma unroll
        for (int i = 0; i < 16; ++i) {
            const int r = i * 4 + quad;
            const f32x4 v = *(const f32x4*)&wt[r * LDSW + lr * 4];
            __builtin_nontemporal_store(
                v, (f32x4*)(C + (size_t)(mbase + r) * VOCAB + nwave + lr * 4));
        }
    }
}

extern "C" void kernel_launch(void* const* d_in, const int* in_sizes, int n_in,
                              void* d_out, int out_size, void* d_ws, size_t ws_size,
                              hipStream_t stream) {
    const int*   x    = (const int*)d_in[0];     // [4096,8]
    const float* emb  = (const float*)d_in[1];   // [32000,128]
    const float* W    = (const float*)d_in[2];   // [32000,128]
    const float* bias = (const float*)d_in[3];   // [32000]
    float* out = (float*)d_out;                  // [4096,32000]

    unsigned short* A  = (unsigned short*)d_ws;            // 1 MB: summed bf16
    unsigned short* Wb = A + (size_t)BATCH * EMBED;        // 8.2 MB: W bf16

    gather_sum_kernel<<<BATCH, EMBED, 0, stream>>>(x, emb, A);
    convert_w_kernel<<<(VOCAB * EMBED / 4) / 256, 256, 0, stream>>>(W, Wb);

    dim3 grid(VOCAB / 256, BATCH / (8 * 64));   // 125 x 8 = 1000 blocks
    cbow_gemm_kernel<<<grid, 256, 0, stream>>>(A, Wb, bias, out);
}